// Round 13
// baseline (199.271 us; speedup 1.0000x reference)
//
#include <hip/hip_runtime.h>

#define BLOCK 256
#define NBLOCKS 2048
#define WAVES_PER_BLOCK (BLOCK / 64)
#define GROUPS_PER_BLOCK (BLOCK / 16)
#define CONV_BLOCKS 4096

// ---- int4 dot primitive: hardware sdot8 if available, else software ----
#if defined(__has_builtin)
#  if __has_builtin(__builtin_amdgcn_sdot8)
#    define SDOT8(a, b, c) __builtin_amdgcn_sdot8((a), (b), (c), false)
#  endif
#endif
#ifndef SDOT8
__device__ __forceinline__ int sdot8_sw(int a, int b, int c) {
    #pragma unroll
    for (int k = 0; k < 8; ++k) {
        int ae = (a << (28 - 4 * k)) >> 28;
        int be = (b << (28 - 4 * k)) >> 28;
        c += ae * be;
    }
    return c;
}
#  define SDOT8(a, b, c) sdot8_sw((a), (b), (c))
#endif

// Pass 0: f32 table -> int4 table (per-row symmetric scale, [-7,7]) + f32 scales.
// Also zeroes the fused-reduction accumulators (d_ws is re-poisoned 0xAA before
// every launch; this kernel is stream-ordered before stage 1, so the zeroing is
// visible there).
__global__ __launch_bounds__(256) void convert_int4_kernel(
    const float4* __restrict__ emb4,        // [rows*64]
    unsigned short* __restrict__ q,         // [rows*64] 4 int4 per ushort
    float* __restrict__ scl,                // [rows]
    double* __restrict__ acc,               // [3] fused accumulators
    unsigned int* __restrict__ cnt,         // [1] done-block counter
    int rows)
{
    if (blockIdx.x == 0 && threadIdx.x == 0) {
        acc[0] = 0.0; acc[1] = 0.0; acc[2] = 0.0;
        *cnt = 0u;
    }
    const int lane = threadIdx.x & 63;
    const int wid  = blockIdx.x * (blockDim.x >> 6) + (threadIdx.x >> 6);
    const int nw   = gridDim.x * (blockDim.x >> 6);
    for (int r = wid; r < rows; r += nw) {
        float4 v = emb4[(size_t)r * 64 + lane];
        float m = fmaxf(fmaxf(fabsf(v.x), fabsf(v.y)), fmaxf(fabsf(v.z), fabsf(v.w)));
        #pragma unroll
        for (int off = 1; off < 64; off <<= 1)
            m = fmaxf(m, __shfl_xor(m, off, 64));
        const float inv = 7.0f / m;
        int q0 = __float2int_rn(v.x * inv) & 15;
        int q1 = __float2int_rn(v.y * inv) & 15;
        int q2 = __float2int_rn(v.z * inv) & 15;
        int q3 = __float2int_rn(v.w * inv) & 15;
        q[(size_t)r * 64 + lane] =
            (unsigned short)(q0 | (q1 << 4) | (q2 << 8) | (q3 << 12));
        if (lane == 0) scl[r] = m * (1.0f / 7.0f);
    }
}

// Stage 1 (int4, fused final): 16-lane group per triplet; row = 128B = 16 x uint2.
// Block partials go straight to device-scope f64 atomics; the last block to
// finish computes and writes the 3 outputs (last-block pattern).
__global__ __launch_bounds__(BLOCK) void triplet_partial_int4(
    const uint2* __restrict__ tabq,     // [rows*16]
    const float* __restrict__ scl,      // [rows]
    const int* __restrict__ trip,       // [T,3] int32
    double* __restrict__ acc,           // [3]
    unsigned int* __restrict__ cnt,     // [1]
    float* __restrict__ out,            // [3]
    int T)
{
    const int lane = threadIdx.x & 63;
    const int lg   = lane & 15;
    const int g0   = blockIdx.x * GROUPS_PER_BLOCK + (threadIdx.x >> 4);
    const int ngroups = gridDim.x * GROUPS_PER_BLOCK;

    float s_loss = 0.f, s_apd = 0.f, s_and = 0.f;

    for (int t = g0; t < T; t += ngroups) {
        const int ia = trip[3 * t + 0];
        const int ip = trip[3 * t + 1];
        const int in_ = trip[3 * t + 2];

        const float sa = scl[ia];
        const float sp = scl[ip];
        const float sn = scl[in_];

        uint2 qa = tabq[(size_t)ia * 16 + lg];
        uint2 qp = tabq[(size_t)ip * 16 + lg];
        uint2 qn = tabq[(size_t)in_ * 16 + lg];

        int idap = 0, idan = 0;
        idap = SDOT8((int)qa.x, (int)qp.x, idap);
        idap = SDOT8((int)qa.y, (int)qp.y, idap);
        idan = SDOT8((int)qa.x, (int)qn.x, idan);
        idan = SDOT8((int)qa.y, (int)qn.y, idan);

        // exact integer reduce across the 16-lane group
        #pragma unroll
        for (int off = 1; off < 16; off <<= 1) {
            idap += __shfl_xor(idap, off, 64);
            idan += __shfl_xor(idan, off, 64);
        }

        float dap = (float)idap * (sa * sp);
        float dan = (float)idan * (sa * sn);

        dap = fminf(1.f, fmaxf(-1.f, dap));
        dan = fminf(1.f, fmaxf(-1.f, dan));

        s_loss += expf((dan - dap) * (1.0f / 0.7f));
        s_apd  += dap;
        s_and  += dan;
    }

    // 16 identical copies per group; butterfly then x1/16 (exact pow2)
    #pragma unroll
    for (int off = 1; off < 64; off <<= 1) {
        s_loss += __shfl_xor(s_loss, off, 64);
        s_apd  += __shfl_xor(s_apd,  off, 64);
        s_and  += __shfl_xor(s_and,  off, 64);
    }

    __shared__ double red[3][WAVES_PER_BLOCK];
    const int wid = threadIdx.x >> 6;
    if (lane == 0) {
        red[0][wid] = (double)s_loss * 0.0625;
        red[1][wid] = (double)s_apd  * 0.0625;
        red[2][wid] = (double)s_and  * 0.0625;
    }
    __syncthreads();
    if (threadIdx.x == 0) {
        double l = 0.0, ap = 0.0, an = 0.0;
        #pragma unroll
        for (int w = 0; w < WAVES_PER_BLOCK; ++w) {
            l += red[0][w]; ap += red[1][w]; an += red[2][w];
        }
        atomicAdd(&acc[0], l);
        atomicAdd(&acc[1], ap);
        atomicAdd(&acc[2], an);
        __threadfence();
        const unsigned int old = atomicAdd(cnt, 1u);
        if (old == (unsigned int)(gridDim.x - 1)) {
            // last block: coherent read-back via atomic RMW (+0.0), then write out
            const double tl  = atomicAdd(&acc[0], 0.0);
            const double tap = atomicAdd(&acc[1], 0.0);
            const double tan_ = atomicAdd(&acc[2], 0.0);
            const double invT = 1.0 / (double)T;
            out[0] = (float)(tl * invT);
            out[1] = (float)(1.0 - tap * invT);
            out[2] = (float)(1.0 - tan_ * invT);
        }
    }
}

// ---------- f32 fallback path (proven) ----------

__device__ __forceinline__ float dot4(float4 a, float4 b) {
    return a.x * b.x + a.y * b.y + a.z * b.z + a.w * b.w;
}

__global__ __launch_bounds__(BLOCK) void triplet_partial_kernel(
    const float* __restrict__ emb, const int* __restrict__ trip,
    double* __restrict__ partial, int T)
{
    const int lane = threadIdx.x & 63;
    const int lg   = lane & 15;
    const int g0   = blockIdx.x * GROUPS_PER_BLOCK + (threadIdx.x >> 4);
    const int ngroups = gridDim.x * GROUPS_PER_BLOCK;
    const float4* __restrict__ emb4 = (const float4*)emb;

    float s_loss = 0.f, s_apd = 0.f, s_and = 0.f;

    for (int t = g0; t < T; t += ngroups) {
        const int ia = trip[3 * t + 0];
        const int ip = trip[3 * t + 1];
        const int in_ = trip[3 * t + 2];
        const size_t ba = (size_t)ia * 64 + lg;
        const size_t bp = (size_t)ip * 64 + lg;
        const size_t bn = (size_t)in_ * 64 + lg;

        float4 a0 = emb4[ba], a1 = emb4[ba + 16], a2 = emb4[ba + 32], a3 = emb4[ba + 48];
        float4 p0 = emb4[bp], p1 = emb4[bp + 16], p2 = emb4[bp + 32], p3 = emb4[bp + 48];
        float4 n0 = emb4[bn], n1 = emb4[bn + 16], n2 = emb4[bn + 32], n3 = emb4[bn + 48];

        float dap = dot4(a0, p0) + dot4(a1, p1) + dot4(a2, p2) + dot4(a3, p3);
        float dan = dot4(a0, n0) + dot4(a1, n1) + dot4(a2, n2) + dot4(a3, n3);

        #pragma unroll
        for (int off = 1; off < 16; off <<= 1) {
            dap += __shfl_xor(dap, off, 64);
            dan += __shfl_xor(dan, off, 64);
        }

        dap = fminf(1.f, fmaxf(-1.f, dap));
        dan = fminf(1.f, fmaxf(-1.f, dan));

        s_loss += expf((dan - dap) * (1.0f / 0.7f));
        s_apd  += dap;
        s_and  += dan;
    }

    #pragma unroll
    for (int off = 1; off < 64; off <<= 1) {
        s_loss += __shfl_xor(s_loss, off, 64);
        s_apd  += __shfl_xor(s_apd,  off, 64);
        s_and  += __shfl_xor(s_and,  off, 64);
    }

    __shared__ double red[3][WAVES_PER_BLOCK];
    const int wid = threadIdx.x >> 6;
    if (lane == 0) {
        red[0][wid] = (double)s_loss * 0.0625;
        red[1][wid] = (double)s_apd  * 0.0625;
        red[2][wid] = (double)s_and  * 0.0625;
    }
    __syncthreads();
    if (threadIdx.x == 0) {
        double l = 0.0, ap = 0.0, an = 0.0;
        #pragma unroll
        for (int w = 0; w < WAVES_PER_BLOCK; ++w) {
            l += red[0][w]; ap += red[1][w]; an += red[2][w];
        }
        partial[(size_t)blockIdx.x * 3 + 0] = l;
        partial[(size_t)blockIdx.x * 3 + 1] = ap;
        partial[(size_t)blockIdx.x * 3 + 2] = an;
    }
}

// Stage 2 (fallback only): deterministic reduce of per-block partials.
__global__ __launch_bounds__(256) void triplet_final_kernel(
    const double* __restrict__ partial, float* __restrict__ out, int nblocks, int T)
{
    __shared__ double red[256][3];
    double l = 0.0, ap = 0.0, an = 0.0;
    for (int i = threadIdx.x; i < nblocks; i += 256) {
        l  += partial[3 * (size_t)i + 0];
        ap += partial[3 * (size_t)i + 1];
        an += partial[3 * (size_t)i + 2];
    }
    red[threadIdx.x][0] = l;
    red[threadIdx.x][1] = ap;
    red[threadIdx.x][2] = an;
    __syncthreads();
    for (int s = 128; s > 0; s >>= 1) {
        if (threadIdx.x < s) {
            red[threadIdx.x][0] += red[threadIdx.x + s][0];
            red[threadIdx.x][1] += red[threadIdx.x + s][1];
            red[threadIdx.x][2] += red[threadIdx.x + s][2];
        }
        __syncthreads();
    }
    if (threadIdx.x == 0) {
        const double invT = 1.0 / (double)T;
        out[0] = (float)(red[0][0] * invT);
        out[1] = (float)(1.0 - red[0][1] * invT);
        out[2] = (float)(1.0 - red[0][2] * invT);
    }
}

extern "C" void kernel_launch(void* const* d_in, const int* in_sizes, int n_in,
                              void* d_out, int out_size, void* d_ws, size_t ws_size,
                              hipStream_t stream) {
    const float* emb = (const float*)d_in[0];
    const int* trip  = (const int*)d_in[1];
    const int D = 256;
    const int rows = in_sizes[0] / D;
    const int T = in_sizes[1] / 3;

    const size_t qBytes = (size_t)rows * (D / 2);        // 8 MiB int4 table
    const size_t sBytes = (size_t)rows * sizeof(float);  // 256 KiB scales
    const size_t aBytes = 3 * sizeof(double) + sizeof(unsigned int);

    if (ws_size >= qBytes + sBytes + aBytes) {
        unsigned short* q = (unsigned short*)d_ws;
        float* scl        = (float*)((char*)d_ws + qBytes);
        double* acc       = (double*)((char*)d_ws + qBytes + sBytes);
        unsigned int* cnt = (unsigned int*)((char*)d_ws + qBytes + sBytes + 3 * sizeof(double));

        convert_int4_kernel<<<CONV_BLOCKS, 256, 0, stream>>>(
            (const float4*)emb, q, scl, acc, cnt, rows);
        triplet_partial_int4<<<NBLOCKS, BLOCK, 0, stream>>>(
            (const uint2*)q, scl, trip, acc, cnt, (float*)d_out, T);
    } else {
        double* partial = (double*)d_ws;
        triplet_partial_kernel<<<NBLOCKS, BLOCK, 0, stream>>>(emb, trip, partial, T);
        triplet_final_kernel<<<1, 256, 0, stream>>>(partial, (float*)d_out, NBLOCKS, T);
    }
}

// Round 14
// 148.311 us; speedup vs baseline: 1.3436x; 1.3436x over previous
//
#include <hip/hip_runtime.h>

#define BLOCK 256
#define NBLOCKS 2048
#define WAVES_PER_BLOCK (BLOCK / 64)
#define GROUPS_PER_BLOCK (BLOCK / 16)
#define CONV_BLOCKS 4096

// ---- int4 dot primitive: hardware sdot8 if available, else software ----
#if defined(__has_builtin)
#  if __has_builtin(__builtin_amdgcn_sdot8)
#    define SDOT8(a, b, c) __builtin_amdgcn_sdot8((a), (b), (c), false)
#  endif
#endif
#ifndef SDOT8
__device__ __forceinline__ int sdot8_sw(int a, int b, int c) {
    #pragma unroll
    for (int k = 0; k < 8; ++k) {
        int ae = (a << (28 - 4 * k)) >> 28;
        int be = (b << (28 - 4 * k)) >> 28;
        c += ae * be;
    }
    return c;
}
#  define SDOT8(a, b, c) sdot8_sw((a), (b), (c))
#endif

// Pass 0: f32 table -> int4 table (per-row symmetric scale, [-7,7]) + f32 scales.
// Also zeroes the done-block counter for the fused last-block reduction
// (d_ws is re-poisoned 0xAA before every launch; stream order guarantees
// visibility in stage 1).
__global__ __launch_bounds__(256) void convert_int4_kernel(
    const float4* __restrict__ emb4,        // [rows*64]
    unsigned short* __restrict__ q,         // [rows*64] 4 int4 per ushort
    float* __restrict__ scl,                // [rows]
    unsigned int* __restrict__ cnt,         // [1] done-block counter
    int rows)
{
    if (blockIdx.x == 0 && threadIdx.x == 0) *cnt = 0u;
    const int lane = threadIdx.x & 63;
    const int wid  = blockIdx.x * (blockDim.x >> 6) + (threadIdx.x >> 6);
    const int nw   = gridDim.x * (blockDim.x >> 6);
    for (int r = wid; r < rows; r += nw) {
        float4 v = emb4[(size_t)r * 64 + lane];
        float m = fmaxf(fmaxf(fabsf(v.x), fabsf(v.y)), fmaxf(fabsf(v.z), fabsf(v.w)));
        #pragma unroll
        for (int off = 1; off < 64; off <<= 1)
            m = fmaxf(m, __shfl_xor(m, off, 64));
        const float inv = 7.0f / m;
        int q0 = __float2int_rn(v.x * inv) & 15;
        int q1 = __float2int_rn(v.y * inv) & 15;
        int q2 = __float2int_rn(v.z * inv) & 15;
        int q3 = __float2int_rn(v.w * inv) & 15;
        q[(size_t)r * 64 + lane] =
            (unsigned short)(q0 | (q1 << 4) | (q2 << 8) | (q3 << 12));
        if (lane == 0) scl[r] = m * (1.0f / 7.0f);
    }
}

// Stage 1 (int4, fused last-block finalize): 16-lane group per triplet.
// Per-block partials are plain stores (no f64 CAS atomics); one hardware u32
// atomicAdd per block; the last block re-reduces all partials and writes out.
__global__ __launch_bounds__(BLOCK) void triplet_partial_int4(
    const uint2* __restrict__ tabq,     // [rows*16]
    const float* __restrict__ scl,      // [rows]
    const int* __restrict__ trip,       // [T,3] int32
    double* __restrict__ partial,       // [gridDim.x,3]
    unsigned int* __restrict__ cnt,     // [1]
    float* __restrict__ out,            // [3]
    int T)
{
    const int lane = threadIdx.x & 63;
    const int lg   = lane & 15;
    const int g0   = blockIdx.x * GROUPS_PER_BLOCK + (threadIdx.x >> 4);
    const int ngroups = gridDim.x * GROUPS_PER_BLOCK;

    float s_loss = 0.f, s_apd = 0.f, s_and = 0.f;

    for (int t = g0; t < T; t += ngroups) {
        const int ia = trip[3 * t + 0];
        const int ip = trip[3 * t + 1];
        const int in_ = trip[3 * t + 2];

        const float sa = scl[ia];
        const float sp = scl[ip];
        const float sn = scl[in_];

        uint2 qa = tabq[(size_t)ia * 16 + lg];
        uint2 qp = tabq[(size_t)ip * 16 + lg];
        uint2 qn = tabq[(size_t)in_ * 16 + lg];

        int idap = 0, idan = 0;
        idap = SDOT8((int)qa.x, (int)qp.x, idap);
        idap = SDOT8((int)qa.y, (int)qp.y, idap);
        idan = SDOT8((int)qa.x, (int)qn.x, idan);
        idan = SDOT8((int)qa.y, (int)qn.y, idan);

        // exact integer reduce across the 16-lane group
        #pragma unroll
        for (int off = 1; off < 16; off <<= 1) {
            idap += __shfl_xor(idap, off, 64);
            idan += __shfl_xor(idan, off, 64);
        }

        float dap = (float)idap * (sa * sp);
        float dan = (float)idan * (sa * sn);

        dap = fminf(1.f, fmaxf(-1.f, dap));
        dan = fminf(1.f, fmaxf(-1.f, dan));

        s_loss += expf((dan - dap) * (1.0f / 0.7f));
        s_apd  += dap;
        s_and  += dan;
    }

    // 16 identical copies per group; butterfly then x1/16 (exact pow2)
    #pragma unroll
    for (int off = 1; off < 64; off <<= 1) {
        s_loss += __shfl_xor(s_loss, off, 64);
        s_apd  += __shfl_xor(s_apd,  off, 64);
        s_and  += __shfl_xor(s_and,  off, 64);
    }

    __shared__ double red[3][WAVES_PER_BLOCK];
    __shared__ int isLast;
    const int wid = threadIdx.x >> 6;
    if (lane == 0) {
        red[0][wid] = (double)s_loss * 0.0625;
        red[1][wid] = (double)s_apd  * 0.0625;
        red[2][wid] = (double)s_and  * 0.0625;
    }
    __syncthreads();
    if (threadIdx.x == 0) {
        double l = 0.0, ap = 0.0, an = 0.0;
        #pragma unroll
        for (int w = 0; w < WAVES_PER_BLOCK; ++w) {
            l += red[0][w]; ap += red[1][w]; an += red[2][w];
        }
        partial[(size_t)blockIdx.x * 3 + 0] = l;
        partial[(size_t)blockIdx.x * 3 + 1] = ap;
        partial[(size_t)blockIdx.x * 3 + 2] = an;
        __threadfence();   // release: make partials device-visible
        const unsigned int old = atomicAdd(cnt, 1u);   // hardware u32 add
        isLast = (old == (unsigned int)(gridDim.x - 1)) ? 1 : 0;
    }
    __syncthreads();

    if (isLast) {
        // Last block: reduce all per-block partials (deterministic order
        // per thread stride + fixed tree) and write the 3 outputs.
        __shared__ double fr[BLOCK][3];
        double l = 0.0, ap = 0.0, an = 0.0;
        for (int i = threadIdx.x; i < NBLOCKS; i += BLOCK) {
            l  += partial[3 * (size_t)i + 0];
            ap += partial[3 * (size_t)i + 1];
            an += partial[3 * (size_t)i + 2];
        }
        fr[threadIdx.x][0] = l;
        fr[threadIdx.x][1] = ap;
        fr[threadIdx.x][2] = an;
        __syncthreads();
        for (int s = BLOCK / 2; s > 0; s >>= 1) {
            if (threadIdx.x < s) {
                fr[threadIdx.x][0] += fr[threadIdx.x + s][0];
                fr[threadIdx.x][1] += fr[threadIdx.x + s][1];
                fr[threadIdx.x][2] += fr[threadIdx.x + s][2];
            }
            __syncthreads();
        }
        if (threadIdx.x == 0) {
            const double invT = 1.0 / (double)T;
            out[0] = (float)(fr[0][0] * invT);
            out[1] = (float)(1.0 - fr[0][1] * invT);
            out[2] = (float)(1.0 - fr[0][2] * invT);
        }
    }
}

// ---------- f32 fallback path (proven) ----------

__device__ __forceinline__ float dot4(float4 a, float4 b) {
    return a.x * b.x + a.y * b.y + a.z * b.z + a.w * b.w;
}

__global__ __launch_bounds__(BLOCK) void triplet_partial_kernel(
    const float* __restrict__ emb, const int* __restrict__ trip,
    double* __restrict__ partial, int T)
{
    const int lane = threadIdx.x & 63;
    const int lg   = lane & 15;
    const int g0   = blockIdx.x * GROUPS_PER_BLOCK + (threadIdx.x >> 4);
    const int ngroups = gridDim.x * GROUPS_PER_BLOCK;
    const float4* __restrict__ emb4 = (const float4*)emb;

    float s_loss = 0.f, s_apd = 0.f, s_and = 0.f;

    for (int t = g0; t < T; t += ngroups) {
        const int ia = trip[3 * t + 0];
        const int ip = trip[3 * t + 1];
        const int in_ = trip[3 * t + 2];
        const size_t ba = (size_t)ia * 64 + lg;
        const size_t bp = (size_t)ip * 64 + lg;
        const size_t bn = (size_t)in_ * 64 + lg;

        float4 a0 = emb4[ba], a1 = emb4[ba + 16], a2 = emb4[ba + 32], a3 = emb4[ba + 48];
        float4 p0 = emb4[bp], p1 = emb4[bp + 16], p2 = emb4[bp + 32], p3 = emb4[bp + 48];
        float4 n0 = emb4[bn], n1 = emb4[bn + 16], n2 = emb4[bn + 32], n3 = emb4[bn + 48];

        float dap = dot4(a0, p0) + dot4(a1, p1) + dot4(a2, p2) + dot4(a3, p3);
        float dan = dot4(a0, n0) + dot4(a1, n1) + dot4(a2, n2) + dot4(a3, n3);

        #pragma unroll
        for (int off = 1; off < 16; off <<= 1) {
            dap += __shfl_xor(dap, off, 64);
            dan += __shfl_xor(dan, off, 64);
        }

        dap = fminf(1.f, fmaxf(-1.f, dap));
        dan = fminf(1.f, fmaxf(-1.f, dan));

        s_loss += expf((dan - dap) * (1.0f / 0.7f));
        s_apd  += dap;
        s_and  += dan;
    }

    #pragma unroll
    for (int off = 1; off < 64; off <<= 1) {
        s_loss += __shfl_xor(s_loss, off, 64);
        s_apd  += __shfl_xor(s_apd,  off, 64);
        s_and  += __shfl_xor(s_and,  off, 64);
    }

    __shared__ double red[3][WAVES_PER_BLOCK];
    const int wid = threadIdx.x >> 6;
    if (lane == 0) {
        red[0][wid] = (double)s_loss * 0.0625;
        red[1][wid] = (double)s_apd  * 0.0625;
        red[2][wid] = (double)s_and  * 0.0625;
    }
    __syncthreads();
    if (threadIdx.x == 0) {
        double l = 0.0, ap = 0.0, an = 0.0;
        #pragma unroll
        for (int w = 0; w < WAVES_PER_BLOCK; ++w) {
            l += red[0][w]; ap += red[1][w]; an += red[2][w];
        }
        partial[(size_t)blockIdx.x * 3 + 0] = l;
        partial[(size_t)blockIdx.x * 3 + 1] = ap;
        partial[(size_t)blockIdx.x * 3 + 2] = an;
    }
}

// Stage 2 (fallback only): deterministic reduce of per-block partials.
__global__ __launch_bounds__(256) void triplet_final_kernel(
    const double* __restrict__ partial, float* __restrict__ out, int nblocks, int T)
{
    __shared__ double red[256][3];
    double l = 0.0, ap = 0.0, an = 0.0;
    for (int i = threadIdx.x; i < nblocks; i += 256) {
        l  += partial[3 * (size_t)i + 0];
        ap += partial[3 * (size_t)i + 1];
        an += partial[3 * (size_t)i + 2];
    }
    red[threadIdx.x][0] = l;
    red[threadIdx.x][1] = ap;
    red[threadIdx.x][2] = an;
    __syncthreads();
    for (int s = 128; s > 0; s >>= 1) {
        if (threadIdx.x < s) {
            red[threadIdx.x][0] += red[threadIdx.x + s][0];
            red[threadIdx.x][1] += red[threadIdx.x + s][1];
            red[threadIdx.x][2] += red[threadIdx.x + s][2];
        }
        __syncthreads();
    }
    if (threadIdx.x == 0) {
        const double invT = 1.0 / (double)T;
        out[0] = (float)(red[0][0] * invT);
        out[1] = (float)(1.0 - red[0][1] * invT);
        out[2] = (float)(1.0 - red[0][2] * invT);
    }
}

extern "C" void kernel_launch(void* const* d_in, const int* in_sizes, int n_in,
                              void* d_out, int out_size, void* d_ws, size_t ws_size,
                              hipStream_t stream) {
    const float* emb = (const float*)d_in[0];
    const int* trip  = (const int*)d_in[1];
    const int D = 256;
    const int rows = in_sizes[0] / D;
    const int T = in_sizes[1] / 3;

    const size_t qBytes = (size_t)rows * (D / 2);        // 8 MiB int4 table
    const size_t sBytes = (size_t)rows * sizeof(float);  // 256 KiB scales
    const size_t pBytes = (size_t)NBLOCKS * 3 * sizeof(double);
    const size_t cBytes = sizeof(unsigned int);

    if (ws_size >= qBytes + sBytes + pBytes + cBytes) {
        unsigned short* q = (unsigned short*)d_ws;
        float* scl        = (float*)((char*)d_ws + qBytes);
        double* partial   = (double*)((char*)d_ws + qBytes + sBytes);
        unsigned int* cnt = (unsigned int*)((char*)d_ws + qBytes + sBytes + pBytes);

        convert_int4_kernel<<<CONV_BLOCKS, 256, 0, stream>>>(
            (const float4*)emb, q, scl, cnt, rows);
        triplet_partial_int4<<<NBLOCKS, BLOCK, 0, stream>>>(
            (const uint2*)q, scl, trip, partial, cnt, (float*)d_out, T);
    } else {
        double* partial = (double*)d_ws;
        triplet_partial_kernel<<<NBLOCKS, BLOCK, 0, stream>>>(emb, trip, partial, T);
        triplet_final_kernel<<<1, 256, 0, stream>>>(partial, (float*)d_out, NBLOCKS, T);
    }
}

// Round 15
// 107.220 us; speedup vs baseline: 1.8585x; 1.3832x over previous
//
#include <hip/hip_runtime.h>

#define BLOCK 256
#define NBLOCKS 2048
#define WAVES_PER_BLOCK (BLOCK / 64)
#define GROUPS_PER_BLOCK (BLOCK / 16)
#define CONV_BLOCKS 4096

// ---- int4 dot primitive: hardware sdot8 if available, else software ----
#if defined(__has_builtin)
#  if __has_builtin(__builtin_amdgcn_sdot8)
#    define SDOT8(a, b, c) __builtin_amdgcn_sdot8((a), (b), (c), false)
#  endif
#endif
#ifndef SDOT8
__device__ __forceinline__ int sdot8_sw(int a, int b, int c) {
    #pragma unroll
    for (int k = 0; k < 8; ++k) {
        int ae = (a << (28 - 4 * k)) >> 28;
        int be = (b << (28 - 4 * k)) >> 28;
        c += ae * be;
    }
    return c;
}
#  define SDOT8(a, b, c) sdot8_sw((a), (b), (c))
#endif

// Pass 0: f32 table -> int4 table (per-row symmetric scale, [-7,7]) + f32 scales.
// One 64-lane wave per row: lane loads float4 (4 elems), wave-reduce max|x|,
// quantize to 4 nibbles packed in one ushort; 64 ushorts = 128B/row, coalesced.
__global__ __launch_bounds__(256) void convert_int4_kernel(
    const float4* __restrict__ emb4,        // [rows*64]
    unsigned short* __restrict__ q,         // [rows*64] 4 int4 per ushort
    float* __restrict__ scl,                // [rows]
    int rows)
{
    const int lane = threadIdx.x & 63;
    const int wid  = blockIdx.x * (blockDim.x >> 6) + (threadIdx.x >> 6);
    const int nw   = gridDim.x * (blockDim.x >> 6);
    for (int r = wid; r < rows; r += nw) {
        float4 v = emb4[(size_t)r * 64 + lane];
        float m = fmaxf(fmaxf(fabsf(v.x), fabsf(v.y)), fmaxf(fabsf(v.z), fabsf(v.w)));
        #pragma unroll
        for (int off = 1; off < 64; off <<= 1)
            m = fmaxf(m, __shfl_xor(m, off, 64));
        const float inv = 7.0f / m;
        int q0 = __float2int_rn(v.x * inv) & 15;
        int q1 = __float2int_rn(v.y * inv) & 15;
        int q2 = __float2int_rn(v.z * inv) & 15;
        int q3 = __float2int_rn(v.w * inv) & 15;
        q[(size_t)r * 64 + lane] =
            (unsigned short)(q0 | (q1 << 4) | (q2 << 8) | (q3 << 12));
        if (lane == 0) scl[r] = m * (1.0f / 7.0f);
    }
}

// Stage 1 (int4): 16-lane group per triplet; row = 128B = 16 x uint2.
// Lane lg holds bytes [lg*8, lg*8+8) of each row -> 2 sdot8 per pair,
// exact integer 16-lane butterfly reduce, then scale/clip/exp in f32.
__global__ __launch_bounds__(BLOCK) void triplet_partial_int4(
    const uint2* __restrict__ tabq,     // [rows*16]
    const float* __restrict__ scl,      // [rows]
    const int* __restrict__ trip,       // [T,3] int32
    double* __restrict__ partial,       // [gridDim.x,3]
    int T)
{
    const int lane = threadIdx.x & 63;
    const int lg   = lane & 15;
    const int g0   = blockIdx.x * GROUPS_PER_BLOCK + (threadIdx.x >> 4);
    const int ngroups = gridDim.x * GROUPS_PER_BLOCK;

    float s_loss = 0.f, s_apd = 0.f, s_and = 0.f;

    for (int t = g0; t < T; t += ngroups) {
        const int ia = trip[3 * t + 0];
        const int ip = trip[3 * t + 1];
        const int in_ = trip[3 * t + 2];

        const float sa = scl[ia];
        const float sp = scl[ip];
        const float sn = scl[in_];

        uint2 qa = tabq[(size_t)ia * 16 + lg];
        uint2 qp = tabq[(size_t)ip * 16 + lg];
        uint2 qn = tabq[(size_t)in_ * 16 + lg];

        int idap = 0, idan = 0;
        idap = SDOT8((int)qa.x, (int)qp.x, idap);
        idap = SDOT8((int)qa.y, (int)qp.y, idap);
        idan = SDOT8((int)qa.x, (int)qn.x, idan);
        idan = SDOT8((int)qa.y, (int)qn.y, idan);

        // exact integer reduce across the 16-lane group
        #pragma unroll
        for (int off = 1; off < 16; off <<= 1) {
            idap += __shfl_xor(idap, off, 64);
            idan += __shfl_xor(idan, off, 64);
        }

        float dap = (float)idap * (sa * sp);
        float dan = (float)idan * (sa * sn);

        dap = fminf(1.f, fmaxf(-1.f, dap));
        dan = fminf(1.f, fmaxf(-1.f, dan));

        s_loss += expf((dan - dap) * (1.0f / 0.7f));
        s_apd  += dap;
        s_and  += dan;
    }

    // 16 identical copies per group; butterfly then x1/16 (exact pow2)
    #pragma unroll
    for (int off = 1; off < 64; off <<= 1) {
        s_loss += __shfl_xor(s_loss, off, 64);
        s_apd  += __shfl_xor(s_apd,  off, 64);
        s_and  += __shfl_xor(s_and,  off, 64);
    }

    __shared__ double red[3][WAVES_PER_BLOCK];
    const int wid = threadIdx.x >> 6;
    if (lane == 0) {
        red[0][wid] = (double)s_loss * 0.0625;
        red[1][wid] = (double)s_apd  * 0.0625;
        red[2][wid] = (double)s_and  * 0.0625;
    }
    __syncthreads();
    if (threadIdx.x == 0) {
        double l = 0.0, ap = 0.0, an = 0.0;
        #pragma unroll
        for (int w = 0; w < WAVES_PER_BLOCK; ++w) {
            l += red[0][w]; ap += red[1][w]; an += red[2][w];
        }
        partial[(size_t)blockIdx.x * 3 + 0] = l;
        partial[(size_t)blockIdx.x * 3 + 1] = ap;
        partial[(size_t)blockIdx.x * 3 + 2] = an;
    }
}

// ---------- f32 fallback path (proven) ----------

__device__ __forceinline__ float dot4(float4 a, float4 b) {
    return a.x * b.x + a.y * b.y + a.z * b.z + a.w * b.w;
}

__global__ __launch_bounds__(BLOCK) void triplet_partial_kernel(
    const float* __restrict__ emb, const int* __restrict__ trip,
    double* __restrict__ partial, int T)
{
    const int lane = threadIdx.x & 63;
    const int lg   = lane & 15;
    const int g0   = blockIdx.x * GROUPS_PER_BLOCK + (threadIdx.x >> 4);
    const int ngroups = gridDim.x * GROUPS_PER_BLOCK;
    const float4* __restrict__ emb4 = (const float4*)emb;

    float s_loss = 0.f, s_apd = 0.f, s_and = 0.f;

    for (int t = g0; t < T; t += ngroups) {
        const int ia = trip[3 * t + 0];
        const int ip = trip[3 * t + 1];
        const int in_ = trip[3 * t + 2];
        const size_t ba = (size_t)ia * 64 + lg;
        const size_t bp = (size_t)ip * 64 + lg;
        const size_t bn = (size_t)in_ * 64 + lg;

        float4 a0 = emb4[ba], a1 = emb4[ba + 16], a2 = emb4[ba + 32], a3 = emb4[ba + 48];
        float4 p0 = emb4[bp], p1 = emb4[bp + 16], p2 = emb4[bp + 32], p3 = emb4[bp + 48];
        float4 n0 = emb4[bn], n1 = emb4[bn + 16], n2 = emb4[bn + 32], n3 = emb4[bn + 48];

        float dap = dot4(a0, p0) + dot4(a1, p1) + dot4(a2, p2) + dot4(a3, p3);
        float dan = dot4(a0, n0) + dot4(a1, n1) + dot4(a2, n2) + dot4(a3, n3);

        #pragma unroll
        for (int off = 1; off < 16; off <<= 1) {
            dap += __shfl_xor(dap, off, 64);
            dan += __shfl_xor(dan, off, 64);
        }

        dap = fminf(1.f, fmaxf(-1.f, dap));
        dan = fminf(1.f, fmaxf(-1.f, dan));

        s_loss += expf((dan - dap) * (1.0f / 0.7f));
        s_apd  += dap;
        s_and  += dan;
    }

    #pragma unroll
    for (int off = 1; off < 64; off <<= 1) {
        s_loss += __shfl_xor(s_loss, off, 64);
        s_apd  += __shfl_xor(s_apd,  off, 64);
        s_and  += __shfl_xor(s_and,  off, 64);
    }

    __shared__ double red[3][WAVES_PER_BLOCK];
    const int wid = threadIdx.x >> 6;
    if (lane == 0) {
        red[0][wid] = (double)s_loss * 0.0625;
        red[1][wid] = (double)s_apd  * 0.0625;
        red[2][wid] = (double)s_and  * 0.0625;
    }
    __syncthreads();
    if (threadIdx.x == 0) {
        double l = 0.0, ap = 0.0, an = 0.0;
        #pragma unroll
        for (int w = 0; w < WAVES_PER_BLOCK; ++w) {
            l += red[0][w]; ap += red[1][w]; an += red[2][w];
        }
        partial[(size_t)blockIdx.x * 3 + 0] = l;
        partial[(size_t)blockIdx.x * 3 + 1] = ap;
        partial[(size_t)blockIdx.x * 3 + 2] = an;
    }
}

// Stage 2: deterministic reduce of per-block partials.
__global__ __launch_bounds__(256) void triplet_final_kernel(
    const double* __restrict__ partial, float* __restrict__ out, int nblocks, int T)
{
    __shared__ double red[256][3];
    double l = 0.0, ap = 0.0, an = 0.0;
    for (int i = threadIdx.x; i < nblocks; i += 256) {
        l  += partial[3 * (size_t)i + 0];
        ap += partial[3 * (size_t)i + 1];
        an += partial[3 * (size_t)i + 2];
    }
    red[threadIdx.x][0] = l;
    red[threadIdx.x][1] = ap;
    red[threadIdx.x][2] = an;
    __syncthreads();
    for (int s = 128; s > 0; s >>= 1) {
        if (threadIdx.x < s) {
            red[threadIdx.x][0] += red[threadIdx.x + s][0];
            red[threadIdx.x][1] += red[threadIdx.x + s][1];
            red[threadIdx.x][2] += red[threadIdx.x + s][2];
        }
        __syncthreads();
    }
    if (threadIdx.x == 0) {
        const double invT = 1.0 / (double)T;
        out[0] = (float)(red[0][0] * invT);
        out[1] = (float)(1.0 - red[0][1] * invT);
        out[2] = (float)(1.0 - red[0][2] * invT);
    }
}

extern "C" void kernel_launch(void* const* d_in, const int* in_sizes, int n_in,
                              void* d_out, int out_size, void* d_ws, size_t ws_size,
                              hipStream_t stream) {
    const float* emb = (const float*)d_in[0];
    const int* trip  = (const int*)d_in[1];
    const int D = 256;
    const int rows = in_sizes[0] / D;
    const int T = in_sizes[1] / 3;

    const size_t qBytes = (size_t)rows * (D / 2);        // 8 MiB int4 table
    const size_t sBytes = (size_t)rows * sizeof(float);  // 256 KiB scales
    const size_t pBytes = (size_t)NBLOCKS * 3 * sizeof(double);

    if (ws_size >= qBytes + sBytes + pBytes) {
        unsigned short* q = (unsigned short*)d_ws;
        float* scl        = (float*)((char*)d_ws + qBytes);
        double* partial   = (double*)((char*)d_ws + qBytes + sBytes);

        convert_int4_kernel<<<CONV_BLOCKS, 256, 0, stream>>>(
            (const float4*)emb, q, scl, rows);
        triplet_partial_int4<<<NBLOCKS, BLOCK, 0, stream>>>(
            (const uint2*)q, scl, trip, partial, T);
        triplet_final_kernel<<<1, 256, 0, stream>>>(partial, (float*)d_out, NBLOCKS, T);
    } else {
        double* partial = (double*)d_ws;
        triplet_partial_kernel<<<NBLOCKS, BLOCK, 0, stream>>>(emb, trip, partial, T);
        triplet_final_kernel<<<1, 256, 0, stream>>>(partial, (float*)d_out, NBLOCKS, T);
    }
}